// Round 1
// baseline (179812.317 us; speedup 1.0000x reference)
//
#include <hip/hip_runtime.h>

#define BB 128
#define TT 1024
#define DD 512
#define HH 1024
#define NBLK 256

__device__ __forceinline__ float d4(const float4 a, const float4 b) {
    return a.x*b.x + a.y*b.y + a.z*b.z + a.w*b.w;
}

// Sense-reversing grid barrier, agent (device) scope. Safe for re-entry:
// cnt is reset before gen is bumped (release), stragglers still spinning on
// phase g block any next-phase completion until they have arrived.
__device__ __forceinline__ void grid_barrier(int* cnt, int* gen) {
    __syncthreads();
    if (threadIdx.x == 0) {
        __threadfence();  // make this block's h-writes visible (agent scope)
        int g = __hip_atomic_load(gen, __ATOMIC_RELAXED, __HIP_MEMORY_SCOPE_AGENT);
        if (__hip_atomic_fetch_add(cnt, 1, __ATOMIC_ACQ_REL, __HIP_MEMORY_SCOPE_AGENT) == NBLK - 1) {
            __hip_atomic_store(cnt, 0, __ATOMIC_RELAXED, __HIP_MEMORY_SCOPE_AGENT);
            __hip_atomic_fetch_add(gen, 1, __ATOMIC_RELEASE, __HIP_MEMORY_SCOPE_AGENT);
        } else {
            while (__hip_atomic_load(gen, __ATOMIC_RELAXED, __HIP_MEMORY_SCOPE_AGENT) == g) {
                __builtin_amdgcn_s_sleep(1);
            }
        }
        __threadfence();  // acquire: invalidate caches so we see other XCDs' h
    }
    __syncthreads();
}

// Persistent GRU kernel. Grid = 256 blocks x 256 threads, all co-resident
// (no LDS, <=128 VGPR via launch_bounds(256,2) -> >=1 block/CU guaranteed).
// Block tile: 32 batch rows x 16 hidden cols. Thread: 2 batch rows x 1 col.
// blockIdx = (bb<<6) | jb so jb%8 == XCD -> per-XCD weight slice ~2.3MB (L2-fits).
__global__ __launch_bounds__(256, 2) void gru_persistent(
    const float* __restrict__ x, const float* __restrict__ w_ih,
    const float* __restrict__ w_hh, const float* __restrict__ bias,
    const float* __restrict__ bn, float* __restrict__ ws)
{
    float* h0buf = ws;
    float* h1buf = ws + (size_t)BB * HH;
    int*   bar   = (int*)(ws + (size_t)2 * BB * HH);

    const int tid = threadIdx.x;
    const int j   = ((blockIdx.x & 63) << 4) + (tid & 15);       // hidden col [0,1024)
    const int bA  = ((blockIdx.x >> 6) << 5) + ((tid >> 4) << 1); // batch row pair
    const int bC  = bA + 1;

    const float4* wr = (const float4*)(w_hh + (size_t)j * HH);
    const float4* wz = (const float4*)(w_hh + (size_t)(j + HH) * HH);
    const float4* wn = (const float4*)(w_hh + (size_t)(j + 2 * HH) * HH);
    const float4* vr = (const float4*)(w_ih + (size_t)j * DD);
    const float4* vz = (const float4*)(w_ih + (size_t)(j + HH) * DD);
    const float4* vn = (const float4*)(w_ih + (size_t)(j + 2 * HH) * DD);

    const float br  = bias[j];
    const float bz  = bias[j + HH];
    const float bnb = bias[j + 2 * HH];
    const float bnj = bn[j];

    for (int t = 0; t < TT; ++t) {
        const float* hin  = (t & 1) ? h1buf : h0buf;
        float*       hout = (t & 1) ? h0buf : h1buf;
        const float4* hA = (const float4*)(hin + (size_t)bA * HH);
        const float4* hB = (const float4*)(hin + (size_t)bC * HH);
        const float4* xA = (const float4*)(x + (size_t)bA * TT * DD + (size_t)t * DD);
        const float4* xB = (const float4*)(x + (size_t)bC * TT * DD + (size_t)t * DD);

        float rA = 0.f, rB = 0.f, zA = 0.f, zB = 0.f;
        float gA = 0.f, gB = 0.f, iA = 0.f, iB = 0.f;  // g = h-part of n, i = x-part of n

        #pragma unroll 2
        for (int k = 0; k < HH / 4; ++k) {
            float4 a = wr[k], c = wz[k], e = wn[k];
            float4 p = hA[k], q = hB[k];
            rA += d4(a, p); rB += d4(a, q);
            zA += d4(c, p); zB += d4(c, q);
            gA += d4(e, p); gB += d4(e, q);
        }
        #pragma unroll 2
        for (int k = 0; k < DD / 4; ++k) {
            float4 a = vr[k], c = vz[k], e = vn[k];
            float4 p = xA[k], q = xB[k];
            rA += d4(a, p); rB += d4(a, q);
            zA += d4(c, p); zB += d4(c, q);
            iA += d4(e, p); iB += d4(e, q);
        }

        const float hpA = hin[(size_t)bA * HH + j];
        const float hpB = hin[(size_t)bC * HH + j];

        const float rrA = 1.f / (1.f + __expf(-(rA + br)));
        const float rrB = 1.f / (1.f + __expf(-(rB + br)));
        const float zzA = 1.f / (1.f + __expf(-(zA + bz)));
        const float zzB = 1.f / (1.f + __expf(-(zB + bz)));
        const float nA  = tanhf(iA + bnb + rrA * (gA + bnj));
        const float nB  = tanhf(iB + bnb + rrB * (gB + bnj));

        hout[(size_t)bA * HH + j] = nA + zzA * (hpA - nA);
        hout[(size_t)bC * HH + j] = nB + zzB * (hpB - nB);

        grid_barrier(bar, bar + 1);
    }
}

// Final projection: out[b] = h_final[b,:] . w_out + b_out. h_final is in h0buf.
__global__ void gru_out(const float* __restrict__ hbuf, const float* __restrict__ w_out,
                        const float* __restrict__ b_out, float* __restrict__ out)
{
    __shared__ float red[4];
    const int b = blockIdx.x, tid = threadIdx.x;
    const float4* hv = (const float4*)(hbuf + (size_t)b * HH);
    const float4* wv = (const float4*)w_out;
    float s = d4(hv[tid], wv[tid]);  // HH/4 == 256 == blockDim
    #pragma unroll
    for (int off = 32; off > 0; off >>= 1) s += __shfl_down(s, off, 64);
    if ((tid & 63) == 0) red[tid >> 6] = s;
    __syncthreads();
    if (tid == 0) out[b] = red[0] + red[1] + red[2] + red[3] + b_out[0];
}

extern "C" void kernel_launch(void* const* d_in, const int* in_sizes, int n_in,
                              void* d_out, int out_size, void* d_ws, size_t ws_size,
                              hipStream_t stream) {
    const float* x     = (const float*)d_in[0];
    const float* w_ih  = (const float*)d_in[1];
    const float* w_hh  = (const float*)d_in[2];
    const float* bias  = (const float*)d_in[3];
    const float* bn    = (const float*)d_in[4];
    const float* w_out = (const float*)d_in[5];
    const float* b_out = (const float*)d_in[6];
    float* ws = (float*)d_ws;

    // ws layout: [h buf0: 512KB][h buf1: 512KB][barrier cnt/gen]
    // ws is re-poisoned 0xAA before every timed call -> must re-init h0 and barrier.
    hipMemsetAsync(d_ws, 0, (size_t)BB * HH * sizeof(float), stream);              // h0 = 0
    hipMemsetAsync((char*)d_ws + (size_t)2 * BB * HH * sizeof(float), 0, 256, stream); // barrier words

    gru_persistent<<<NBLK, 256, 0, stream>>>(x, w_ih, w_hh, bias, bn, ws);
    gru_out<<<BB, 256, 0, stream>>>(ws, w_out, b_out, (float*)d_out);
}

// Round 2
// 25060.321 us; speedup vs baseline: 7.1752x; 7.1752x over previous
//
#include <hip/hip_runtime.h>

#define BB 128
#define TT 1024
#define DD 512
#define HH 1024
#define NBLK 256
#define NTHR 384
#define KI 48            // K iterations: 32 over h (K=1024), 16 over x (K=512)
#define ASTRIDE 1544     // LDS A-row stride in bf16 elems (padded; 3088B = 16B-aligned rows)

typedef __attribute__((ext_vector_type(8))) short short8;
typedef __attribute__((ext_vector_type(4))) float float4v;

__device__ __forceinline__ short f2bf(float f) {
    __bf16 b = (__bf16)f;                      // RNE f32->bf16
    return __builtin_bit_cast(short, b);
}
__device__ __forceinline__ float bf2f(unsigned short s) {
    union { unsigned int i; float f; } u; u.i = ((unsigned int)s) << 16; return u.f;
}

// Sense-reversing grid barrier, agent scope (proven correct in round 1).
__device__ __forceinline__ void grid_barrier(int* cnt, int* gen) {
    __syncthreads();
    if (threadIdx.x == 0) {
        __threadfence();
        int g = __hip_atomic_load(gen, __ATOMIC_RELAXED, __HIP_MEMORY_SCOPE_AGENT);
        if (__hip_atomic_fetch_add(cnt, 1, __ATOMIC_ACQ_REL, __HIP_MEMORY_SCOPE_AGENT) == NBLK - 1) {
            __hip_atomic_store(cnt, 0, __ATOMIC_RELAXED, __HIP_MEMORY_SCOPE_AGENT);
            __hip_atomic_fetch_add(gen, 1, __ATOMIC_RELEASE, __HIP_MEMORY_SCOPE_AGENT);
        } else {
            while (__hip_atomic_load(gen, __ATOMIC_RELAXED, __HIP_MEMORY_SCOPE_AGENT) == g) {
                __builtin_amdgcn_s_sleep(1);
            }
        }
        __threadfence();
    }
    __syncthreads();
}

// Persistent MFMA GRU. 256 blocks (1/CU), 384 threads = 6 waves.
// Block: 32 batch rows (m0..m0+31) x 16 hidden cols (jg*16..) x 3 gates.
// Wave (w = tid>>6): mt = w&1 (m-tile of 16), gate = w>>1 (0=r,1=z,2=n).
// B fragments (weights, bf16) live in 192 VGPRs per wave, loaded ONCE.
// A (h || x_t) staged in LDS per step, bf16, padded stride.
__global__ __launch_bounds__(NTHR, 2) void gru_mfma(
    const float* __restrict__ x, const float* __restrict__ w_ih,
    const float* __restrict__ w_hh, const float* __restrict__ bias,
    const float* __restrict__ bn, unsigned short* __restrict__ ws_h)
{
    __shared__ __align__(16) unsigned short smem[32 * ASTRIDE];  // 98816 B
    float* tiles = (float*)smem;  // epilogue alias: [2 m-tiles][4 slots][16][16] fp32 = 8KB

    unsigned short* h0 = ws_h;
    unsigned short* h1 = ws_h + (size_t)BB * HH;
    int* bar = (int*)(ws_h + (size_t)2 * BB * HH);

    const int tid  = threadIdx.x;
    const int wave = tid >> 6;
    const int lane = tid & 63;
    const int mt   = wave & 1;
    const int gate = wave >> 1;          // 0=r, 1=z, 2=n
    const int jg   = blockIdx.x >> 2;    // 0..63 hidden-col group
    const int m0   = (blockIdx.x & 3) * 32;
    const int ln   = lane & 15;
    const int q    = lane >> 4;

    // ---- B fragments: weight row = gate*H + jg*16 + ln, k = i*32 + q*8 .. +8 ----
    const int nrow = gate * HH + jg * 16 + ln;
    const float* whh_row = w_hh + (size_t)nrow * HH;
    const float* wih_row = w_ih + (size_t)nrow * DD;
    short8 Bfrag[KI];
    #pragma unroll
    for (int i = 0; i < KI; ++i) {
        const float* src = (i < 32) ? (whh_row + i * 32 + q * 8)
                                    : (wih_row + (i - 32) * 32 + q * 8);
        float4 f0 = *(const float4*)src;
        float4 f1 = *(const float4*)(src + 4);
        short8 b;
        b[0] = f2bf(f0.x); b[1] = f2bf(f0.y); b[2] = f2bf(f0.z); b[3] = f2bf(f0.w);
        b[4] = f2bf(f1.x); b[5] = f2bf(f1.y); b[6] = f2bf(f1.z); b[7] = f2bf(f1.w);
        Bfrag[i] = b;
    }

    const unsigned short* abase = &smem[(mt * 16 + ln) * ASTRIDE + q * 8];

    for (int t = 0; t < TT; ++t) {
        const unsigned short* hin  = (t & 1) ? h1 : h0;
        unsigned short*       hout = (t & 1) ? h0 : h1;

        // ---- stage h rows -> LDS cols [0,1024), bf16 16B chunks ----
        for (int c = tid; c < 4096; c += NTHR) {
            int r = c >> 7, col = (c & 127) * 8;
            int4 v = *(const int4*)(hin + (size_t)(m0 + r) * HH + col);
            *(int4*)&smem[r * ASTRIDE + col] = v;
        }
        // ---- stage x_t rows (fp32 -> bf16) -> LDS cols [1024,1536) ----
        for (int c = tid; c < 2048; c += NTHR) {
            int r = c >> 6, col = (c & 63) * 8;
            const float* src = x + (size_t)(m0 + r) * TT * DD + (size_t)t * DD + col;
            float4 f0 = *(const float4*)src;
            float4 f1 = *(const float4*)(src + 4);
            short8 b;
            b[0] = f2bf(f0.x); b[1] = f2bf(f0.y); b[2] = f2bf(f0.z); b[3] = f2bf(f0.w);
            b[4] = f2bf(f1.x); b[5] = f2bf(f1.y); b[6] = f2bf(f1.z); b[7] = f2bf(f1.w);
            *(short8*)&smem[r * ASTRIDE + 1024 + col] = b;
        }
        __syncthreads();

        // ---- K-loop: accA over h-part, accB over x-part ----
        float4v accA = {0.f, 0.f, 0.f, 0.f};
        float4v accB = {0.f, 0.f, 0.f, 0.f};
        #pragma unroll
        for (int i = 0; i < 32; ++i) {
            short8 a = *(const short8*)(abase + i * 32);
            accA = __builtin_amdgcn_mfma_f32_16x16x32_bf16(a, Bfrag[i], accA, 0, 0, 0);
        }
        #pragma unroll
        for (int i = 32; i < KI; ++i) {
            short8 a = *(const short8*)(abase + i * 32);
            accB = __builtin_amdgcn_mfma_f32_16x16x32_bf16(a, Bfrag[i], accB, 0, 0, 0);
        }
        __syncthreads();  // all waves done reading A before tiles alias is written

        // ---- write C tiles to LDS: slots 0=r, 1=z, 2=hg_n, 3=ig_n ----
        // C/D layout: col = lane&15, row = q*4 + reg (m89-verified)
        if (gate == 2) {
            float* tA = tiles + (mt * 4 + 2) * 256;
            float* tB = tiles + (mt * 4 + 3) * 256;
            #pragma unroll
            for (int r = 0; r < 4; ++r) {
                tA[(q * 4 + r) * 16 + ln] = accA[r];
                tB[(q * 4 + r) * 16 + ln] = accB[r];
            }
        } else {
            float* tA = tiles + (mt * 4 + gate) * 256;
            #pragma unroll
            for (int r = 0; r < 4; ++r)
                tA[(q * 4 + r) * 16 + ln] = accA[r] + accB[r];
        }
        __syncthreads();

        // ---- epilogue: 512 (m,j) outputs ----
        for (int idx = tid; idx < 512; idx += NTHR) {
            int m = idx >> 4, j = idx & 15;
            int mtile = m >> 4, ml = m & 15;
            const float* base = tiles + mtile * 1024 + ml * 16 + j;
            float cr  = base[0];
            float cz  = base[256];
            float chn = base[512];
            float cin = base[768];
            int jgl = jg * 16 + j;
            float br  = bias[jgl];
            float bz  = bias[HH + jgl];
            float b2  = bias[2 * HH + jgl];
            float bnj = bn[jgl];
            float hp  = bf2f(hin[(size_t)(m0 + m) * HH + jgl]);
            float rr  = 1.f / (1.f + __expf(-(cr + br)));
            float zz  = 1.f / (1.f + __expf(-(cz + bz)));
            float nn  = tanhf(cin + b2 + rr * (chn + bnj));
            float hv  = nn + zz * (hp - nn);
            hout[(size_t)(m0 + m) * HH + jgl] = (unsigned short)f2bf(hv);
        }

        grid_barrier(bar, bar + 1);
    }
}

// out[b] = h_final[b,:] . w_out + b_out  (h_final bf16 in h0)
__global__ void gru_out(const unsigned short* __restrict__ h,
                        const float* __restrict__ w_out,
                        const float* __restrict__ b_out, float* __restrict__ out)
{
    __shared__ float red[4];
    const int b = blockIdx.x, tid = threadIdx.x;
    const int col = tid * 4;
    ushort4 hv = *(const ushort4*)(h + (size_t)b * HH + col);
    float4  wv = *(const float4*)(w_out + col);
    float s = bf2f(hv.x) * wv.x + bf2f(hv.y) * wv.y + bf2f(hv.z) * wv.z + bf2f(hv.w) * wv.w;
    #pragma unroll
    for (int off = 32; off > 0; off >>= 1) s += __shfl_down(s, off, 64);
    if ((tid & 63) == 0) red[tid >> 6] = s;
    __syncthreads();
    if (tid == 0) out[b] = red[0] + red[1] + red[2] + red[3] + b_out[0];
}

extern "C" void kernel_launch(void* const* d_in, const int* in_sizes, int n_in,
                              void* d_out, int out_size, void* d_ws, size_t ws_size,
                              hipStream_t stream) {
    const float* x     = (const float*)d_in[0];
    const float* w_ih  = (const float*)d_in[1];
    const float* w_hh  = (const float*)d_in[2];
    const float* bias  = (const float*)d_in[3];
    const float* bn    = (const float*)d_in[4];
    const float* w_out = (const float*)d_in[5];
    const float* b_out = (const float*)d_in[6];
    unsigned short* ws_h = (unsigned short*)d_ws;

    // ws layout: [h0 bf16 256KB][h1 bf16 256KB][barrier ints]
    // ws re-poisoned 0xAA each call -> re-init h0 and barrier words.
    hipMemsetAsync(d_ws, 0, (size_t)BB * HH * 2, stream);                       // h0 = 0 (bf16)
    hipMemsetAsync((char*)d_ws + (size_t)2 * BB * HH * 2, 0, 256, stream);      // barrier

    gru_mfma<<<NBLK, NTHR, 0, stream>>>(x, w_ih, w_hh, bias, bn, ws_h);
    gru_out<<<BB, 256, 0, stream>>>(ws_h, w_out, b_out, (float*)d_out);
}

// Round 3
// 24487.659 us; speedup vs baseline: 7.3430x; 1.0234x over previous
//
#include <hip/hip_runtime.h>

#define BB 128
#define TT 1024
#define DD 512
#define HH 1024
#define NBLK 256
#define NTHR 384
#define KI 48            // K iters: 32 over h (K=1024), 16 over x (K=512)
#define AST 1536         // LDS A-row stride in bf16 elems (bank-aligned; XOR swizzle handles conflicts)
#define NGRP 16          // barrier groups (blockIdx & 15 -> same XCD under %8 round-robin)

typedef __attribute__((ext_vector_type(8))) short short8;
typedef __attribute__((ext_vector_type(4))) float float4v;

__device__ __forceinline__ short f2bf(float f) {
    __bf16 b = (__bf16)f;
    return __builtin_bit_cast(short, b);
}
__device__ __forceinline__ float bf2f(unsigned short s) {
    union { unsigned int i; float f; } u; u.i = ((unsigned int)s) << 16; return u.f;
}
__device__ __forceinline__ float fast_tanh(float v) {
    v = fminf(15.f, fmaxf(-15.f, v));
    float e = __expf(2.f * v);
    return (e - 1.f) / (e + 1.f);
}

// Two-level sense-reversing grid barrier, agent scope.
// Level 1: 16 groups of 16 blocks (group = blockIdx&15 -> one XCD each under
// round-robin; correctness does not depend on the mapping). Level 2: 16 group
// roots on a global counter. Release fans out global gen -> group gen -> members.
// Lines (32 ints = 128B each): [0]=Gcnt [1]=Ggen [2+g]=gcnt[g] [18+g]=ggen[g].
__device__ __forceinline__ void grid_barrier2(int* bar) {
    __syncthreads();
    if (threadIdx.x == 0) {
        __threadfence();  // release: this block's h stores visible agent-wide
        const int g = blockIdx.x & (NGRP - 1);
        int* gcnt = bar + 32 * (2 + g);
        int* ggen = bar + 32 * (18 + g);
        int* Gcnt = bar;
        int* Ggen = bar + 32;
        int mygen = __hip_atomic_load(ggen, __ATOMIC_RELAXED, __HIP_MEMORY_SCOPE_AGENT);
        if (__hip_atomic_fetch_add(gcnt, 1, __ATOMIC_ACQ_REL, __HIP_MEMORY_SCOPE_AGENT)
            == (NBLK / NGRP) - 1) {
            __hip_atomic_store(gcnt, 0, __ATOMIC_RELAXED, __HIP_MEMORY_SCOPE_AGENT);
            int Gg0 = __hip_atomic_load(Ggen, __ATOMIC_RELAXED, __HIP_MEMORY_SCOPE_AGENT);
            if (__hip_atomic_fetch_add(Gcnt, 1, __ATOMIC_ACQ_REL, __HIP_MEMORY_SCOPE_AGENT)
                == NGRP - 1) {
                __hip_atomic_store(Gcnt, 0, __ATOMIC_RELAXED, __HIP_MEMORY_SCOPE_AGENT);
                __hip_atomic_fetch_add(Ggen, 1, __ATOMIC_RELEASE, __HIP_MEMORY_SCOPE_AGENT);
            } else {
                while (__hip_atomic_load(Ggen, __ATOMIC_RELAXED, __HIP_MEMORY_SCOPE_AGENT) == Gg0)
                    __builtin_amdgcn_s_sleep(1);
            }
            __hip_atomic_fetch_add(ggen, 1, __ATOMIC_RELEASE, __HIP_MEMORY_SCOPE_AGENT);
        } else {
            while (__hip_atomic_load(ggen, __ATOMIC_RELAXED, __HIP_MEMORY_SCOPE_AGENT) == mygen)
                __builtin_amdgcn_s_sleep(2);
        }
        __threadfence();  // acquire: see other blocks' h stores
    }
    __syncthreads();
}

// x fp32 -> bf16 pre-convert (time-parallel, runs once per call).
__global__ void xcvt(const float* __restrict__ x, unsigned short* __restrict__ xb) {
    const size_t i = ((size_t)blockIdx.x * blockDim.x + threadIdx.x) * 8;
    float4 f0 = *(const float4*)(x + i);
    float4 f1 = *(const float4*)(x + i + 4);
    short8 b;
    b[0] = f2bf(f0.x); b[1] = f2bf(f0.y); b[2] = f2bf(f0.z); b[3] = f2bf(f0.w);
    b[4] = f2bf(f1.x); b[5] = f2bf(f1.y); b[6] = f2bf(f1.z); b[7] = f2bf(f1.w);
    *(short8*)( (unsigned short*)xb + i ) = b;
}

// Persistent MFMA GRU. 256 blocks (1/CU), 384 thr = 6 waves.
// Wave: mt = w&1 (16-row m-tile), gate = w>>1. Weights in 192 regs/lane, loaded once.
// LDS A layout: 32 rows x 1536 elems (h cols 0..1023 | x cols 1024..1535), bf16,
// 16B chunk c of row r stored at chunk c^(r&7)  -> uniform bank use for ds_read_b128.
template <bool XBF>
__global__ __launch_bounds__(NTHR, 2) void gru_mfma(
    const void* __restrict__ xsrc, const float* __restrict__ w_ih,
    const float* __restrict__ w_hh, const float* __restrict__ bias,
    const float* __restrict__ bn,
    unsigned short* __restrict__ h0, unsigned short* __restrict__ h1,
    int* __restrict__ bar)
{
    __shared__ __align__(16) unsigned short smem[32 * AST];  // 98304 B
    float* tiles = (float*)smem;  // epilogue alias (first 8 KB), used after sync

    const int tid  = threadIdx.x;
    const int wave = tid >> 6;
    const int lane = tid & 63;
    const int mt   = wave & 1;
    const int gate = wave >> 1;
    const int jg   = blockIdx.x >> 2;
    const int m0   = (blockIdx.x & 3) * 32;
    const int ln   = lane & 15;
    const int q    = lane >> 4;

    // ---- B fragments (weights), loaded once: row = gate*H + jg*16 + ln ----
    const int nrow = gate * HH + jg * 16 + ln;
    const float* whh_row = w_hh + (size_t)nrow * HH;
    const float* wih_row = w_ih + (size_t)nrow * DD;
    short8 Bfrag[KI];
    #pragma unroll
    for (int i = 0; i < KI; ++i) {
        const float* src = (i < 32) ? (whh_row + i * 32 + q * 8)
                                    : (wih_row + (i - 32) * 32 + q * 8);
        float4 f0 = *(const float4*)src;
        float4 f1 = *(const float4*)(src + 4);
        short8 b;
        b[0] = f2bf(f0.x); b[1] = f2bf(f0.y); b[2] = f2bf(f0.z); b[3] = f2bf(f0.w);
        b[4] = f2bf(f1.x); b[5] = f2bf(f1.y); b[6] = f2bf(f1.z); b[7] = f2bf(f1.w);
        Bfrag[i] = b;
    }

    const int arow = mt * 16 + ln;
    const int asw  = arow & 7;

    for (int t = 0; t < TT; ++t) {
        const unsigned short* hin  = (t & 1) ? h1 : h0;
        unsigned short*       hout = (t & 1) ? h0 : h1;

        // ---- stage h rows -> LDS chunks 0..127 (swizzled) ----
        for (int c = tid; c < 4096; c += NTHR) {
            int r = c >> 7, cc = c & 127;
            int4 v = *(const int4*)(hin + (size_t)(m0 + r) * HH + cc * 8);
            *(int4*)&smem[r * AST + (cc ^ (r & 7)) * 8] = v;
        }
        // ---- stage x_t rows -> LDS chunks 128..191 (swizzled) ----
        for (int c = tid; c < 2048; c += NTHR) {
            int r = c >> 6, cx = c & 63;
            int chunk = (128 + cx) ^ (r & 7);
            if (XBF) {
                const unsigned short* xb = (const unsigned short*)xsrc;
                int4 v = *(const int4*)(xb + (size_t)(m0 + r) * TT * DD + (size_t)t * DD + cx * 8);
                *(int4*)&smem[r * AST + chunk * 8] = v;
            } else {
                const float* xf = (const float*)xsrc;
                const float* src = xf + (size_t)(m0 + r) * TT * DD + (size_t)t * DD + cx * 8;
                float4 f0 = *(const float4*)src;
                float4 f1 = *(const float4*)(src + 4);
                short8 b;
                b[0] = f2bf(f0.x); b[1] = f2bf(f0.y); b[2] = f2bf(f0.z); b[3] = f2bf(f0.w);
                b[4] = f2bf(f1.x); b[5] = f2bf(f1.y); b[6] = f2bf(f1.z); b[7] = f2bf(f1.w);
                *(short8*)&smem[r * AST + chunk * 8] = b;
            }
        }
        __syncthreads();

        // ---- K-loop ----
        float4v accA = {0.f, 0.f, 0.f, 0.f};
        float4v accB = {0.f, 0.f, 0.f, 0.f};
        #pragma unroll
        for (int i = 0; i < 32; ++i) {
            short8 a = *(const short8*)&smem[arow * AST + (((i * 4 + q) ^ asw) * 8)];
            accA = __builtin_amdgcn_mfma_f32_16x16x32_bf16(a, Bfrag[i], accA, 0, 0, 0);
        }
        #pragma unroll
        for (int i = 32; i < KI; ++i) {
            short8 a = *(const short8*)&smem[arow * AST + (((i * 4 + q) ^ asw) * 8)];
            accB = __builtin_amdgcn_mfma_f32_16x16x32_bf16(a, Bfrag[i], accB, 0, 0, 0);
        }

        // ---- read h_prev for epilogue from LDS (before tiles alias is written) ----
        float hpv[2]; int nh = 0;
        for (int idx = tid; idx < 512; idx += NTHR) {
            int m = idx >> 4, j = idx & 15;
            int cj = jg * 16 + j;
            int chunk = (cj >> 3) ^ (m & 7);
            hpv[nh++] = bf2f(smem[m * AST + chunk * 8 + (cj & 7)]);
        }
        __syncthreads();  // all A reads done before tiles alias write

        // ---- C tiles -> LDS: slots 0=r, 1=z, 2=hg_n, 3=ig_n ----
        // C/D layout: col = lane&15, row = q*4 + reg
        if (gate == 2) {
            float* tA = tiles + (mt * 4 + 2) * 256;
            float* tB = tiles + (mt * 4 + 3) * 256;
            #pragma unroll
            for (int r = 0; r < 4; ++r) {
                tA[(q * 4 + r) * 16 + ln] = accA[r];
                tB[(q * 4 + r) * 16 + ln] = accB[r];
            }
        } else {
            float* tA = tiles + (mt * 4 + gate) * 256;
            #pragma unroll
            for (int r = 0; r < 4; ++r)
                tA[(q * 4 + r) * 16 + ln] = accA[r] + accB[r];
        }
        __syncthreads();

        // ---- epilogue ----
        nh = 0;
        for (int idx = tid; idx < 512; idx += NTHR) {
            int m = idx >> 4, j = idx & 15;
            int mtile = m >> 4, ml = m & 15;
            const float* base = tiles + mtile * 1024 + ml * 16 + j;
            float cr  = base[0];
            float cz  = base[256];
            float chn = base[512];
            float cin = base[768];
            int jgl = jg * 16 + j;
            float rr = 1.f / (1.f + __expf(-(cr + bias[jgl])));
            float zz = 1.f / (1.f + __expf(-(cz + bias[HH + jgl])));
            float nn = fast_tanh(cin + bias[2 * HH + jgl] + rr * (chn + bn[jgl]));
            float hp = hpv[nh++];
            float hv = nn + zz * (hp - nn);
            hout[(size_t)(m0 + m) * HH + jgl] = (unsigned short)f2bf(hv);
        }

        grid_barrier2(bar);
    }
}

// out[b] = h_final[b,:] . w_out + b_out  (h_final bf16 in h0)
__global__ void gru_out(const unsigned short* __restrict__ h,
                        const float* __restrict__ w_out,
                        const float* __restrict__ b_out, float* __restrict__ out)
{
    __shared__ float red[4];
    const int b = blockIdx.x, tid = threadIdx.x;
    const int col = tid * 4;
    ushort4 hv = *(const ushort4*)(h + (size_t)b * HH + col);
    float4  wv = *(const float4*)(w_out + col);
    float s = bf2f(hv.x) * wv.x + bf2f(hv.y) * wv.y + bf2f(hv.z) * wv.z + bf2f(hv.w) * wv.w;
    #pragma unroll
    for (int off = 32; off > 0; off >>= 1) s += __shfl_down(s, off, 64);
    if ((tid & 63) == 0) red[tid >> 6] = s;
    __syncthreads();
    if (tid == 0) out[b] = red[0] + red[1] + red[2] + red[3] + b_out[0];
}

extern "C" void kernel_launch(void* const* d_in, const int* in_sizes, int n_in,
                              void* d_out, int out_size, void* d_ws, size_t ws_size,
                              hipStream_t stream) {
    const float* x     = (const float*)d_in[0];
    const float* w_ih  = (const float*)d_in[1];
    const float* w_hh  = (const float*)d_in[2];
    const float* bias  = (const float*)d_in[3];
    const float* bn    = (const float*)d_in[4];
    const float* w_out = (const float*)d_in[5];
    const float* b_out = (const float*)d_in[6];

    const size_t xbytes = (size_t)BB * TT * DD * 2;          // 128 MB bf16 x
    const size_t hbytes = (size_t)BB * HH * 2;               // 256 KB per h buffer
    const bool use_xbf = ws_size >= xbytes + 2 * hbytes + 8192;

    char* base = (char*)d_ws;
    unsigned short* xb = (unsigned short*)base;
    char* hb = use_xbf ? base + xbytes : base;
    unsigned short* h0 = (unsigned short*)hb;
    unsigned short* h1 = (unsigned short*)(hb + hbytes);
    int* bar = (int*)(hb + 2 * hbytes);

    // ws re-poisoned 0xAA each call: re-init h0 and barrier lines every call.
    hipMemsetAsync(h0, 0, hbytes, stream);
    hipMemsetAsync(bar, 0, 8192, stream);

    if (use_xbf) {
        xcvt<<<(BB * TT * DD / 8 + 255) / 256, 256, 0, stream>>>(x, xb);
        gru_mfma<true><<<NBLK, NTHR, 0, stream>>>(xb, w_ih, w_hh, bias, bn, h0, h1, bar);
    } else {
        gru_mfma<false><<<NBLK, NTHR, 0, stream>>>(x, w_ih, w_hh, bias, bn, h0, h1, bar);
    }
    gru_out<<<BB, 256, 0, stream>>>(h0, w_out, b_out, (float*)d_out);
}

// Round 4
// 15474.156 us; speedup vs baseline: 11.6202x; 1.5825x over previous
//
#include <hip/hip_runtime.h>

#define BB 128
#define TT 1024
#define DD 512
#define HH 1024
#define NBLK 256
#define NTHR 384
#define KI 48            // K iters: 32 over h (K=1024), 16 over x (K=512)
#define AST 1536         // LDS A-row stride (bf16 elems); XOR chunk swizzle for banks
#define NGRP 16          // barrier groups: blockIdx&15 -> one XCD under %8 round-robin

typedef __attribute__((ext_vector_type(8))) short short8;
typedef __attribute__((ext_vector_type(4))) float float4v;
typedef unsigned long long u64;

__device__ __forceinline__ short f2bf(float f) {
    __bf16 b = (__bf16)f;
    return __builtin_bit_cast(short, b);
}
__device__ __forceinline__ float bf2f(unsigned short s) {
    union { unsigned int i; float f; } u; u.i = ((unsigned int)s) << 16; return u.f;
}
__device__ __forceinline__ float fast_tanh(float v) {
    v = fminf(15.f, fmaxf(-15.f, v));
    float e = __expf(2.f * v);
    return (e - 1.f) / (e + 1.f);
}

// ---- fence-free agent-scope primitives (RELAXED => no buffer_wbl2/buffer_inv) ----
__device__ __forceinline__ void memwait() {
    asm volatile("s_waitcnt vmcnt(0)" ::: "memory");
}
__device__ __forceinline__ int aload(int* p) {
    return __hip_atomic_load(p, __ATOMIC_RELAXED, __HIP_MEMORY_SCOPE_AGENT);
}
__device__ __forceinline__ void astore(int* p, int v) {
    __hip_atomic_store(p, v, __ATOMIC_RELAXED, __HIP_MEMORY_SCOPE_AGENT);
}
__device__ __forceinline__ int aadd(int* p, int v) {
    return __hip_atomic_fetch_add(p, v, __ATOMIC_RELAXED, __HIP_MEMORY_SCOPE_AGENT);
}
__device__ __forceinline__ u64 aload64(const u64* p) {
    return __hip_atomic_load(p, __ATOMIC_RELAXED, __HIP_MEMORY_SCOPE_AGENT);
}
__device__ __forceinline__ void astore64(u64* p, u64 v) {
    __hip_atomic_store(p, v, __ATOMIC_RELAXED, __HIP_MEMORY_SCOPE_AGENT);
}

// Two-level sense-reversing barrier, ALL-RELAXED atomics + explicit vmcnt drains.
// Correct because every cross-block data access (h) is itself an agent-scope
// atomic (MALL-direct): no dirty L2 lines to flush, no stale caches to inv.
// Ordering chain: h stores -> memwait -> gcnt++ (MALL-serialized) -> ... -> gen bumps.
// Lines (32 ints = 128B each): [0]=Gcnt [32]=Ggen [32*(2+g)]=gcnt[g] [32*(18+g)]=ggen[g].
__device__ __forceinline__ void grid_barrier_nf(int* bar) {
    __syncthreads();
    if (threadIdx.x == 0) {
        const int g = blockIdx.x & (NGRP - 1);
        int* gcnt = bar + 32 * (2 + g);
        int* ggen = bar + 32 * (18 + g);
        int* Gcnt = bar;
        int* Ggen = bar + 32;
        int mygen = aload(ggen);
        memwait();                                   // h stores + mygen at MALL
        if (aadd(gcnt, 1) == (NBLK / NGRP) - 1) {    // result used => RMW complete
            astore(gcnt, 0);
            int Gg0 = aload(Ggen);
            memwait();                               // gcnt reset + Gg0 done
            if (aadd(Gcnt, 1) == NGRP - 1) {
                astore(Gcnt, 0);
                memwait();                           // Gcnt reset before Ggen bump
                aadd(Ggen, 1);
            } else {
                while (aload(Ggen) == Gg0) __builtin_amdgcn_s_sleep(1);
            }
            memwait();                               // drain before releasing members
            aadd(ggen, 1);
        } else {
            while (aload(ggen) == mygen) __builtin_amdgcn_s_sleep(1);
        }
    }
    __syncthreads();
}

// x fp32 -> bf16 pre-convert (time-parallel, once per call).
__global__ void xcvt(const float* __restrict__ x, unsigned short* __restrict__ xb) {
    const size_t i = ((size_t)blockIdx.x * blockDim.x + threadIdx.x) * 8;
    float4 f0 = *(const float4*)(x + i);
    float4 f1 = *(const float4*)(x + i + 4);
    short8 b;
    b[0] = f2bf(f0.x); b[1] = f2bf(f0.y); b[2] = f2bf(f0.z); b[3] = f2bf(f0.w);
    b[4] = f2bf(f1.x); b[5] = f2bf(f1.y); b[6] = f2bf(f1.z); b[7] = f2bf(f1.w);
    *(short8*)((unsigned short*)xb + i) = b;
}

// Persistent MFMA GRU. 256 blocks (1/CU), 384 thr = 6 waves.
// Wave: mt = w&1, gate = w>>1. Weights in 96 VGPRs/lane, loaded once.
// h buffers are accessed ONLY via agent-scope relaxed atomics (MALL-direct).
template <bool XBF>
__global__ __launch_bounds__(NTHR, 2) void gru_mfma(
    const void* __restrict__ xsrc, const float* __restrict__ w_ih,
    const float* __restrict__ w_hh, const float* __restrict__ bias,
    const float* __restrict__ bn,
    unsigned short* __restrict__ h0, unsigned short* __restrict__ h1,
    int* __restrict__ bar)
{
    __shared__ __align__(16) unsigned short smem[32 * AST];  // 98304 B
    float* tiles = (float*)smem;  // epilogue alias (first 8 KB), after sync

    const int tid  = threadIdx.x;
    const int wave = tid >> 6;
    const int lane = tid & 63;
    const int mt   = wave & 1;
    const int gate = wave >> 1;
    const int jg   = blockIdx.x >> 2;
    const int m0   = (blockIdx.x & 3) * 32;
    const int ln   = lane & 15;
    const int q    = lane >> 4;

    // ---- B fragments (weights), loaded once ----
    const int nrow = gate * HH + jg * 16 + ln;
    const float* whh_row = w_hh + (size_t)nrow * HH;
    const float* wih_row = w_ih + (size_t)nrow * DD;
    short8 Bfrag[KI];
    #pragma unroll
    for (int i = 0; i < KI; ++i) {
        const float* src = (i < 32) ? (whh_row + i * 32 + q * 8)
                                    : (wih_row + (i - 32) * 32 + q * 8);
        float4 f0 = *(const float4*)src;
        float4 f1 = *(const float4*)(src + 4);
        short8 b;
        b[0] = f2bf(f0.x); b[1] = f2bf(f0.y); b[2] = f2bf(f0.z); b[3] = f2bf(f0.w);
        b[4] = f2bf(f1.x); b[5] = f2bf(f1.y); b[6] = f2bf(f1.z); b[7] = f2bf(f1.w);
        Bfrag[i] = b;
    }

    // ---- epilogue constants hoisted (waves 0-1 only; wave-uniform branch) ----
    float ebr[4], ebz[4], eb2[4], ebn[4];
    int em = 0, ej0 = 0;
    if (tid < 128) {
        em = tid >> 2; ej0 = (tid & 3) * 4;
        #pragma unroll
        for (int u = 0; u < 4; ++u) {
            int jgl = jg * 16 + ej0 + u;
            ebr[u] = bias[jgl];
            ebz[u] = bias[HH + jgl];
            eb2[u] = bias[2 * HH + jgl];
            ebn[u] = bn[jgl];
        }
    }

    const int arow = mt * 16 + ln;
    const int asw  = arow & 7;

    for (int t = 0; t < TT; ++t) {
        const unsigned short* hin  = (t & 1) ? h1 : h0;
        unsigned short*       hout = (t & 1) ? h0 : h1;

        // ---- stage h rows -> LDS (8B MALL-direct atomic loads, swizzled) ----
        const u64* hin64 = (const u64*)hin;
        for (int c = tid; c < 8192; c += NTHR) {
            int r = c >> 8, cc8 = c & 255;                    // 256 x 8B per row
            u64 v = aload64(hin64 + (size_t)(m0 + r) * 256 + cc8);
            int chunk = (cc8 >> 1) ^ (r & 7);
            *(u64*)&smem[r * AST + chunk * 8 + (cc8 & 1) * 4] = v;
        }
        // ---- stage x_t rows -> LDS chunks 128..191 (normal cached loads) ----
        for (int c = tid; c < 2048; c += NTHR) {
            int r = c >> 6, cx = c & 63;
            int chunk = (128 + cx) ^ (r & 7);
            if (XBF) {
                const unsigned short* xb = (const unsigned short*)xsrc;
                int4 v = *(const int4*)(xb + (size_t)(m0 + r) * TT * DD + (size_t)t * DD + cx * 8);
                *(int4*)&smem[r * AST + chunk * 8] = v;
            } else {
                const float* xf = (const float*)xsrc;
                const float* src = xf + (size_t)(m0 + r) * TT * DD + (size_t)t * DD + cx * 8;
                float4 f0 = *(const float4*)src;
                float4 f1 = *(const float4*)(src + 4);
                short8 b;
                b[0] = f2bf(f0.x); b[1] = f2bf(f0.y); b[2] = f2bf(f0.z); b[3] = f2bf(f0.w);
                b[4] = f2bf(f1.x); b[5] = f2bf(f1.y); b[6] = f2bf(f1.z); b[7] = f2bf(f1.w);
                *(short8*)&smem[r * AST + chunk * 8] = b;
            }
        }
        __syncthreads();

        // ---- K-loop ----
        float4v accA = {0.f, 0.f, 0.f, 0.f};
        float4v accB = {0.f, 0.f, 0.f, 0.f};
        #pragma unroll
        for (int i = 0; i < 32; ++i) {
            short8 a = *(const short8*)&smem[arow * AST + (((i * 4 + q) ^ asw) * 8)];
            accA = __builtin_amdgcn_mfma_f32_16x16x32_bf16(a, Bfrag[i], accA, 0, 0, 0);
        }
        #pragma unroll
        for (int i = 32; i < KI; ++i) {
            short8 a = *(const short8*)&smem[arow * AST + (((i * 4 + q) ^ asw) * 8)];
            accB = __builtin_amdgcn_mfma_f32_16x16x32_bf16(a, Bfrag[i], accB, 0, 0, 0);
        }

        // ---- pre-read h_prev (LDS h area, before tiles alias overwrite) ----
        float hp4[4];
        if (tid < 128) {
            int cj = jg * 16 + ej0;
            int chunk = (cj >> 3) ^ (em & 7);
            const unsigned short* p = &smem[em * AST + chunk * 8 + (cj & 7)];
            hp4[0] = bf2f(p[0]); hp4[1] = bf2f(p[1]);
            hp4[2] = bf2f(p[2]); hp4[3] = bf2f(p[3]);
        }
        __syncthreads();  // all smem reads done before tiles alias write

        // ---- C tiles -> LDS: slots 0=r, 1=z, 2=hg_n, 3=ig_n (C/D: col=ln, row=q*4+reg) ----
        if (gate == 2) {
            float* tA = tiles + (mt * 4 + 2) * 256;
            float* tB = tiles + (mt * 4 + 3) * 256;
            #pragma unroll
            for (int r = 0; r < 4; ++r) {
                tA[(q * 4 + r) * 16 + ln] = accA[r];
                tB[(q * 4 + r) * 16 + ln] = accB[r];
            }
        } else {
            float* tA = tiles + (mt * 4 + gate) * 256;
            #pragma unroll
            for (int r = 0; r < 4; ++r)
                tA[(q * 4 + r) * 16 + ln] = accA[r] + accB[r];
        }
        __syncthreads();

        // ---- epilogue: waves 0-1, 4 consecutive j per thread, packed 8B atomic store ----
        if (tid < 128) {
            const float* base = tiles + (em >> 4) * 1024 + (em & 15) * 16 + ej0;
            u64 pk = 0;
            #pragma unroll
            for (int u = 0; u < 4; ++u) {
                float cr = base[u], cz = base[256 + u], chn = base[512 + u], cin = base[768 + u];
                float rr = 1.f / (1.f + __expf(-(cr + ebr[u])));
                float zz = 1.f / (1.f + __expf(-(cz + ebz[u])));
                float nn = fast_tanh(cin + eb2[u] + rr * (chn + ebn[u]));
                float hv = nn + zz * (hp4[u] - nn);
                pk |= ((u64)(unsigned short)f2bf(hv)) << (16 * u);
            }
            astore64((u64*)&hout[(size_t)(m0 + em) * HH + jg * 16 + ej0], pk);
        }

        grid_barrier_nf(bar);
    }
}

// out[b] = h_final[b,:] . w_out + b_out  (h_final bf16 in h0)
__global__ void gru_out(const unsigned short* __restrict__ h,
                        const float* __restrict__ w_out,
                        const float* __restrict__ b_out, float* __restrict__ out)
{
    __shared__ float red[4];
    const int b = blockIdx.x, tid = threadIdx.x;
    const int col = tid * 4;
    ushort4 hv = *(const ushort4*)(h + (size_t)b * HH + col);
    float4  wv = *(const float4*)(w_out + col);
    float s = bf2f(hv.x) * wv.x + bf2f(hv.y) * wv.y + bf2f(hv.z) * wv.z + bf2f(hv.w) * wv.w;
    #pragma unroll
    for (int off = 32; off > 0; off >>= 1) s += __shfl_down(s, off, 64);
    if ((tid & 63) == 0) red[tid >> 6] = s;
    __syncthreads();
    if (tid == 0) out[b] = red[0] + red[1] + red[2] + red[3] + b_out[0];
}

extern "C" void kernel_launch(void* const* d_in, const int* in_sizes, int n_in,
                              void* d_out, int out_size, void* d_ws, size_t ws_size,
                              hipStream_t stream) {
    const float* x     = (const float*)d_in[0];
    const float* w_ih  = (const float*)d_in[1];
    const float* w_hh  = (const float*)d_in[2];
    const float* bias  = (const float*)d_in[3];
    const float* bn    = (const float*)d_in[4];
    const float* w_out = (const float*)d_in[5];
    const float* b_out = (const float*)d_in[6];

    const size_t xbytes = (size_t)BB * TT * DD * 2;          // 128 MB bf16 x
    const size_t hbytes = (size_t)BB * HH * 2;               // 256 KB per h buffer
    const bool use_xbf = ws_size >= xbytes + 2 * hbytes + 8192;

    char* base = (char*)d_ws;
    unsigned short* xb = (unsigned short*)base;
    char* hb = use_xbf ? base + xbytes : base;
    unsigned short* h0 = (unsigned short*)hb;
    unsigned short* h1 = (unsigned short*)(hb + hbytes);
    int* bar = (int*)(hb + 2 * hbytes);

    // ws re-poisoned 0xAA each call: re-init h0 and barrier lines every call.
    hipMemsetAsync(h0, 0, hbytes, stream);
    hipMemsetAsync(bar, 0, 8192, stream);

    if (use_xbf) {
        xcvt<<<(BB * TT * DD / 8 + 255) / 256, 256, 0, stream>>>(x, xb);
        gru_mfma<true><<<NBLK, NTHR, 0, stream>>>(xb, w_ih, w_hh, bias, bn, h0, h1, bar);
    } else {
        gru_mfma<false><<<NBLK, NTHR, 0, stream>>>(x, w_ih, w_hh, bias, bn, h0, h1, bar);
    }
    gru_out<<<BB, 256, 0, stream>>>(h0, w_out, b_out, (float*)d_out);
}